// Round 1
// 520.665 us; speedup vs baseline: 1.0057x; 1.0057x over previous
//
#include <hip/hip_runtime.h>
#include <math.h>

#define IN_DIM 512
#define HID 512

#define K1_BLOCKS 1024
#define K1_THREADS 512
#define K1_STRIDE (K1_BLOCKS * K1_THREADS)   // 524288; % 128 == 0 -> fixed col4 group per thread
#define P1 K1_BLOCKS
#define K2_BLOCKS 64
#define P2 K2_BLOCKS

typedef float f4 __attribute__((ext_vector_type(4)));

// K1: partial column sums. 32 waves/CU (512 thr x 4 blocks/CU), 4x unrolled with
// independent accumulators so 4 dwordx4 loads are in flight per wave (latency
// hiding: 32 waves * 4 KB = 128 KB in flight per CU >> latency-BW product).
// Non-temporal: x is streamed once, never reused.
__global__ __launch_bounds__(K1_THREADS) void k1_partial(const float* __restrict__ x,
                                                         float* __restrict__ part,
                                                         int total4) {
    const int gtid = blockIdx.x * K1_THREADS + threadIdx.x;
    const f4* __restrict__ x4 = (const f4*)x;
    f4 a0 = {0.f, 0.f, 0.f, 0.f};
    f4 a1 = {0.f, 0.f, 0.f, 0.f};
    f4 a2 = {0.f, 0.f, 0.f, 0.f};
    f4 a3 = {0.f, 0.f, 0.f, 0.f};
    int i = gtid;
    for (; i + 3 * K1_STRIDE < total4; i += 4 * K1_STRIDE) {
        f4 v0 = __builtin_nontemporal_load(x4 + i);
        f4 v1 = __builtin_nontemporal_load(x4 + i + K1_STRIDE);
        f4 v2 = __builtin_nontemporal_load(x4 + i + 2 * K1_STRIDE);
        f4 v3 = __builtin_nontemporal_load(x4 + i + 3 * K1_STRIDE);
        a0 += v0;
        a1 += v1;
        a2 += v2;
        a3 += v3;
    }
    for (; i < total4; i += K1_STRIDE) a0 += __builtin_nontemporal_load(x4 + i);
    f4 acc = (a0 + a1) + (a2 + a3);

    __shared__ f4 lds[K1_THREADS];
    lds[threadIdx.x] = acc;
    __syncthreads();
    // 512 -> 128 writers; thread t < 128 owns column group t (gtid%128 invariant:
    // 512 % 128 == 0 and K1_STRIDE % 128 == 0).
    if (threadIdx.x < 128) {
        f4 s = (lds[threadIdx.x] + lds[threadIdx.x + 128]) +
               (lds[threadIdx.x + 256] + lds[threadIdx.x + 384]);
        ((f4*)(part + (size_t)blockIdx.x * IN_DIM))[threadIdx.x] = s;
    }
}

// K2: reduce 1024 partial rows -> 64 partial rows, fully coalesced.
__global__ __launch_bounds__(IN_DIM) void k2_reduce(const float* __restrict__ part,
                                                    float* __restrict__ part2) {
    const int j = threadIdx.x;
    const int g = blockIdx.x;
    float s = 0.f;
    const int rows = P1 / P2;  // 16
    const float* __restrict__ base = part + (size_t)g * rows * IN_DIM + j;
    for (int r = 0; r < rows; ++r) s += base[(size_t)r * IN_DIM];
    part2[(size_t)g * IN_DIM + j] = s;
}

// K3: finish mean into LDS, then one 64-lane wave per output column computes
// the three gate dot-products + GRU epilogue. h=0 => gh = bias_hh.
__global__ __launch_bounds__(256) void k3_gemv_gates(const float* __restrict__ part2,
                                                     const float* __restrict__ wih,
                                                     const float* __restrict__ bih,
                                                     const float* __restrict__ bhh,
                                                     float* __restrict__ out,
                                                     float inv_n) {
    __shared__ float agg[IN_DIM];
    for (int c = threadIdx.x; c < IN_DIM; c += 256) {
        float s = 0.f;
        for (int r = 0; r < P2; ++r) s += part2[(size_t)r * IN_DIM + c];
        agg[c] = s * inv_n;
    }
    __syncthreads();

    const int w = threadIdx.x >> 6;      // wave in block: 0..3
    const int l = threadIdx.x & 63;      // lane
    const int j = blockIdx.x * 4 + w;    // output column 0..511

    const float4* __restrict__ a4 = (const float4*)agg;
    float4 g1 = a4[l];
    float4 g2 = a4[l + 64];

    float d[3];
#pragma unroll
    for (int gidx = 0; gidx < 3; ++gidx) {
        const float4* __restrict__ w4 =
            (const float4*)(wih + (size_t)(gidx * HID + j) * IN_DIM);
        float4 w1 = w4[l];
        float4 w2 = w4[l + 64];
        d[gidx] = w1.x * g1.x + w1.y * g1.y + w1.z * g1.z + w1.w * g1.w
                + w2.x * g2.x + w2.y * g2.y + w2.z * g2.z + w2.w * g2.w;
    }

#pragma unroll
    for (int off = 32; off > 0; off >>= 1) {
        d[0] += __shfl_down(d[0], off, 64);
        d[1] += __shfl_down(d[1], off, 64);
        d[2] += __shfl_down(d[2], off, 64);
    }

    if (l == 0) {
        float gi_r = d[0] + bih[j];
        float gi_z = d[1] + bih[HID + j];
        float gi_n = d[2] + bih[2 * HID + j];
        float gh_r = bhh[j];
        float gh_z = bhh[HID + j];
        float gh_n = bhh[2 * HID + j];
        float r = 1.f / (1.f + expf(-(gi_r + gh_r)));
        float z = 1.f / (1.f + expf(-(gi_z + gh_z)));
        float n = tanhf(gi_n + r * gh_n);
        out[j] = (1.f - z) * n;   // + z*h, h = 0
    }
}

extern "C" void kernel_launch(void* const* d_in, const int* in_sizes, int n_in,
                              void* d_out, int out_size, void* d_ws, size_t ws_size,
                              hipStream_t stream) {
    const float* x   = (const float*)d_in[0];  // parent_states (N, 512)
    const float* wih = (const float*)d_in[1];  // weight_ih (1536, 512)
    // d_in[2] = weight_hh: unused (h = 0)
    const float* bih = (const float*)d_in[3];  // bias_ih (1536,)
    const float* bhh = (const float*)d_in[4];  // bias_hh (1536,)
    float* out = (float*)d_out;

    const int n_par  = in_sizes[0] / IN_DIM;
    const int total4 = in_sizes[0] / 4;

    float* part  = (float*)d_ws;                      // P1 * 512 floats = 2 MB
    float* part2 = part + (size_t)P1 * IN_DIM;        // P2 * 512 floats = 128 KB

    k1_partial<<<K1_BLOCKS, K1_THREADS, 0, stream>>>(x, part, total4);
    k2_reduce<<<K2_BLOCKS, IN_DIM, 0, stream>>>(part, part2);
    k3_gemv_gates<<<HID / 4, 256, 0, stream>>>(part2, wih, bih, bhh, out,
                                               1.0f / (float)n_par);
}